// Round 1
// baseline (58.433 us; speedup 1.0000x reference)
//
#include <hip/hip_runtime.h>
#include <float.h>
#include <math.h>

#define NB 32
#define LD 512
#define LP 4096
#define HD 128
#define PV 26
// ws layout (bytes):
//   counts  int[NB*PV]    @ 0        (3328)
//   colmax  uint[NB*PV]   @ 3328     (3328)
//   rowmax  float[NB*LD]  @ 6656     (65536)
//   dvec    float[NB*HD]  @ 72192    (16384)

__device__ __forceinline__ unsigned enc_f32(float f) {
    unsigned b = __float_as_uint(f);
    return (b & 0x80000000u) ? ~b : (b | 0x80000000u);
}
__device__ __forceinline__ float dec_f32(unsigned u) {
    unsigned b = (u & 0x80000000u) ? (u ^ 0x80000000u) : ~u;
    return __uint_as_float(b);
}

// K0: per-batch histogram of prot_ids + init colmax encodings
__global__ __launch_bounds__(64) void k_hist(const int* __restrict__ prot_ids,
                                             int* __restrict__ counts,
                                             unsigned* __restrict__ colmax_enc) {
    int b = blockIdx.x;
    int t = threadIdx.x;
    __shared__ int cnt[PV];
    if (t < PV) cnt[t] = 0;
    __syncthreads();
    const int* row = prot_ids + b * LP;
    for (int i = t; i < LP; i += 64) atomicAdd(&cnt[row[i]], 1);
    __syncthreads();
    if (t < PV) {
        counts[b * PV + t] = cnt[t];
        colmax_enc[b * PV + t] = 0u;   // encodes below any real float
    }
}

// K1: scores26 = d_feat · prot_emb^T, row-max (over present v) and col-max (over l)
__global__ __launch_bounds__(128) void k_scores(const int* __restrict__ drug_ids,
                                                const float* __restrict__ drug_emb,
                                                const float* __restrict__ prot_emb,
                                                const int* __restrict__ counts,
                                                float* __restrict__ rowmax,
                                                unsigned* __restrict__ colmax_enc) {
    int b = blockIdx.x >> 2;           // 4 blocks per batch
    int part = blockIdx.x & 3;
    int l = part * 128 + threadIdx.x;  // 128 rows per block, 1 row per thread
    const float* __restrict__ drow = drug_emb + (size_t)drug_ids[b * LD + l] * HD;

    float s[PV];
#pragma unroll
    for (int v = 0; v < PV; ++v) s[v] = 0.f;

    for (int k0 = 0; k0 < HD; k0 += 4) {
        float4 d = *reinterpret_cast<const float4*>(drow + k0);
#pragma unroll
        for (int v = 0; v < PV; ++v) {
            float4 p = *reinterpret_cast<const float4*>(prot_emb + v * HD + k0);
            s[v] = fmaf(d.x, p.x, fmaf(d.y, p.y, fmaf(d.z, p.z, fmaf(d.w, p.w, s[v]))));
        }
    }

    // row max over vocab ids present in this batch's protein sequence
    float rm = -FLT_MAX;
#pragma unroll
    for (int v = 0; v < PV; ++v)
        if (counts[b * PV + v] > 0) rm = fmaxf(rm, s[v]);
    rowmax[b * LD + l] = rm;

    // col max over l: wave-reduce, then one global atomicMax per wave per v
#pragma unroll
    for (int v = 0; v < PV; ++v) {
        float m = s[v];
        for (int off = 32; off; off >>= 1) m = fmaxf(m, __shfl_xor(m, off, 64));
        if ((threadIdx.x & 63) == 0) atomicMax(&colmax_enc[b * PV + v], enc_f32(m));
    }
}

// K2: softmax over drug positions + d_vec
__global__ __launch_bounds__(256) void k_dvec(const int* __restrict__ drug_ids,
                                              const float* __restrict__ drug_emb,
                                              const float* __restrict__ rowmax,
                                              float* __restrict__ dvec) {
    int b = blockIdx.x;
    int t = threadIdx.x;
    __shared__ float att[LD];
    __shared__ float red[8];

    float r0 = rowmax[b * LD + t];
    float r1 = rowmax[b * LD + 256 + t];
    float m = fmaxf(r0, r1);
    for (int off = 32; off; off >>= 1) m = fmaxf(m, __shfl_xor(m, off, 64));
    if ((t & 63) == 0) red[t >> 6] = m;
    __syncthreads();
    m = fmaxf(fmaxf(red[0], red[1]), fmaxf(red[2], red[3]));

    float e0 = expf(r0 - m), e1 = expf(r1 - m);
    att[t] = e0;
    att[t + 256] = e1;
    float ssum = e0 + e1;
    for (int off = 32; off; off >>= 1) ssum += __shfl_xor(ssum, off, 64);
    if ((t & 63) == 0) red[4 + (t >> 6)] = ssum;
    __syncthreads();
    float inv = 1.f / (red[4] + red[5] + red[6] + red[7]);

    // d_vec: 2 half-groups of 128 threads, each owns one h and 256 rows
    int h = t & 127, half = t >> 7;
    const int* __restrict__ ids = drug_ids + b * LD + half * 256;
    float acc = 0.f;
    for (int l = 0; l < 256; ++l)
        acc = fmaf(att[half * 256 + l], drug_emb[(size_t)ids[l] * HD + h], acc);

    __shared__ float part0[HD];
    if (half == 0) part0[h] = acc;
    __syncthreads();
    if (half == 1) dvec[b * HD + h] = (part0[h] + acc) * inv;
}

// K3: protein softmax (via counts), p_vec, and the 256->64->1 MLP
__global__ __launch_bounds__(128) void k_pvec_mlp(const float* __restrict__ prot_emb,
                                                  const int* __restrict__ counts,
                                                  const unsigned* __restrict__ colmax_enc,
                                                  const float* __restrict__ dvec,
                                                  const float* __restrict__ W1,
                                                  const float* __restrict__ b1,
                                                  const float* __restrict__ W2,
                                                  const float* __restrict__ b2,
                                                  float* __restrict__ out) {
    int b = blockIdx.x;
    int t = threadIdx.x;
    __shared__ float ew[PV];
    __shared__ float sM, sInv;
    __shared__ float comb[2 * HD];

    if (t == 0) {
        float M = -FLT_MAX;
        for (int v = 0; v < PV; ++v)
            if (counts[b * PV + v] > 0) M = fmaxf(M, dec_f32(colmax_enc[b * PV + v]));
        sM = M;
    }
    __syncthreads();
    if (t < PV) {
        int c = counts[b * PV + t];
        ew[t] = (c > 0) ? (float)c * expf(dec_f32(colmax_enc[b * PV + t]) - sM) : 0.f;
    }
    __syncthreads();
    if (t == 0) {
        float S = 0.f;
        for (int v = 0; v < PV; ++v) S += ew[v];
        sInv = 1.f / S;
    }
    __syncthreads();

    // p_vec (t = h in [0,128)) and load d_vec
    {
        float acc = 0.f;
#pragma unroll
        for (int v = 0; v < PV; ++v) acc = fmaf(ew[v], prot_emb[v * HD + t], acc);
        comb[HD + t] = acc * sInv;
        comb[t] = dvec[b * HD + t];
    }
    __syncthreads();

    // MLP: h = relu(comb @ W1 + b1); out = h @ W2 + b2
    if (t < 64) {
        float hj = b1[t];
#pragma unroll 8
        for (int k = 0; k < 2 * HD; ++k) hj = fmaf(comb[k], W1[k * 64 + t], hj);
        hj = fmaxf(hj, 0.f);
        float o = hj * W2[t];
        for (int off = 32; off; off >>= 1) o += __shfl_xor(o, off, 64);
        if (t == 0) out[b] = o + b2[0];
    }
}

extern "C" void kernel_launch(void* const* d_in, const int* in_sizes, int n_in,
                              void* d_out, int out_size, void* d_ws, size_t ws_size,
                              hipStream_t stream) {
    const int*   drug_ids = (const int*)d_in[0];
    const int*   prot_ids = (const int*)d_in[1];
    const float* drug_emb = (const float*)d_in[2];
    const float* prot_emb = (const float*)d_in[3];
    const float* W1 = (const float*)d_in[4];
    const float* b1 = (const float*)d_in[5];
    const float* W2 = (const float*)d_in[6];
    const float* b2 = (const float*)d_in[7];
    float* out = (float*)d_out;

    char* ws = (char*)d_ws;
    int*      counts     = (int*)(ws + 0);
    unsigned* colmax_enc = (unsigned*)(ws + 3328);
    float*    rowmax     = (float*)(ws + 6656);
    float*    dvec       = (float*)(ws + 72192);

    k_hist<<<NB, 64, 0, stream>>>(prot_ids, counts, colmax_enc);
    k_scores<<<NB * 4, 128, 0, stream>>>(drug_ids, drug_emb, prot_emb, counts,
                                         rowmax, colmax_enc);
    k_dvec<<<NB, 256, 0, stream>>>(drug_ids, drug_emb, rowmax, dvec);
    k_pvec_mlp<<<NB, 128, 0, stream>>>(prot_emb, counts, colmax_enc, dvec,
                                       W1, b1, W2, b2, out);
}

// Round 2
// 24.168 us; speedup vs baseline: 2.4177x; 2.4177x over previous
//
#include <hip/hip_runtime.h>
#include <float.h>
#include <math.h>

#define NB 32
#define LD 512
#define LP 4096
#define HD 128
#define PV 26
// ws layout (bytes):
//   counts  int[NB*PV]    @ 0        (3328)
//   colmax  uint[NB*PV]   @ 3328     (3328)
//   rowmax  float[NB*LD]  @ 6656     (65536)
//   mask    uint[NB]      @ 72192    (128)

__device__ __forceinline__ unsigned enc_f32(float f) {
    unsigned b = __float_as_uint(f);
    return (b & 0x80000000u) ? ~b : (b | 0x80000000u);
}
__device__ __forceinline__ float dec_f32(unsigned u) {
    unsigned b = (u & 0x80000000u) ? (u ^ 0x80000000u) : ~u;
    return __uint_as_float(b);
}

// K0: per-batch histogram of prot_ids (int4 loads, 4 sub-histograms),
//     presence bitmask, colmax init.
__global__ __launch_bounds__(256) void k_hist(const int* __restrict__ prot_ids,
                                              int* __restrict__ counts,
                                              unsigned* __restrict__ colmax_enc,
                                              unsigned* __restrict__ maskp) {
    int b = blockIdx.x;
    int t = threadIdx.x;
    __shared__ int cnt4[4][PV];
    if (t < 4 * PV) ((int*)cnt4)[t] = 0;
    __syncthreads();
    int w = t >> 6;
    const int4* row = (const int4*)(prot_ids + b * LP);
    #pragma unroll
    for (int i = 0; i < 4; ++i) {
        int4 v = row[t + i * 256];
        atomicAdd(&cnt4[w][v.x], 1);
        atomicAdd(&cnt4[w][v.y], 1);
        atomicAdd(&cnt4[w][v.z], 1);
        atomicAdd(&cnt4[w][v.w], 1);
    }
    __syncthreads();
    if (t < 64) {
        int c = 0;
        if (t < PV) {
            c = cnt4[0][t] + cnt4[1][t] + cnt4[2][t] + cnt4[3][t];
            counts[b * PV + t] = c;
            colmax_enc[b * PV + t] = 0u;   // below any encoded float
        }
        unsigned long long bal = __ballot(c > 0);
        if (t == 0) maskp[b] = (unsigned)bal;
    }
}

// K1: scores26 = d_feat · prot_emb^T with 4-way K-split.
//     wave q handles k in [q*32, q*32+32) for 64 rows; A-quarter preloaded
//     into 32 VGPRs; B address is wave-uniform (readfirstlane) -> scalar path.
__global__ __launch_bounds__(256) void k_scores(const int* __restrict__ drug_ids,
                                                const float* __restrict__ drug_emb,
                                                const float* __restrict__ prot_emb,
                                                const unsigned* __restrict__ maskp,
                                                float* __restrict__ rowmax,
                                                unsigned* __restrict__ colmax_enc) {
    int b = blockIdx.x >> 3;          // 8 row-chunks per batch
    int chunk = blockIdx.x & 7;
    int q = __builtin_amdgcn_readfirstlane(threadIdx.x >> 6);  // k-quarter, SGPR
    int lane = threadIdx.x & 63;
    int l = chunk * 64 + lane;

    const float* __restrict__ A =
        drug_emb + (size_t)drug_ids[b * LD + l] * HD + q * 32;
    float4 a[8];
    #pragma unroll
    for (int i = 0; i < 8; ++i) a[i] = reinterpret_cast<const float4*>(A)[i];

    const float* __restrict__ Bq = prot_emb + q * 32;
    float s[PV];
    #pragma unroll
    for (int v = 0; v < PV; ++v) s[v] = 0.f;

    #pragma unroll
    for (int i = 0; i < 8; ++i) {
        float4 av = a[i];
        #pragma unroll
        for (int v = 0; v < PV; ++v) {
            float4 p = reinterpret_cast<const float4*>(Bq + v * HD)[i];
            s[v] = fmaf(av.x, p.x, fmaf(av.y, p.y,
                   fmaf(av.z, p.z, fmaf(av.w, p.w, s[v]))));
        }
    }

    __shared__ float red[4][64][PV];   // 26.6 KB
    #pragma unroll
    for (int v = 0; v < PV; ++v) red[q][lane][v] = s[v];
    __syncthreads();

    // sum the 4 k-quarters
    for (int o = threadIdx.x; o < 64 * PV; o += 256) {
        int l2 = o / PV, v = o - l2 * PV;
        red[0][l2][v] = red[0][l2][v] + red[1][l2][v] + red[2][l2][v] + red[3][l2][v];
    }
    __syncthreads();

    unsigned msk = maskp[b];
    if (threadIdx.x < 64) {
        int l2 = threadIdx.x;
        float m = -FLT_MAX;
        #pragma unroll
        for (int v = 0; v < PV; ++v)
            if ((msk >> v) & 1) m = fmaxf(m, red[0][l2][v]);
        rowmax[b * LD + chunk * 64 + l2] = m;
    } else if (threadIdx.x < 64 + PV) {
        int v = threadIdx.x - 64;
        float m = -FLT_MAX;
        for (int r = 0; r < 64; ++r) m = fmaxf(m, red[0][r][v]);
        atomicMax(&colmax_enc[b * PV + v], enc_f32(m));
    }
}

// K2: fused tail — drug softmax + d_vec (8-way row split), protein softmax
//     via counts + p_vec, and the 256->64->1 MLP. One block per batch.
__global__ __launch_bounds__(1024) void k_tail(const int* __restrict__ drug_ids,
                                               const float* __restrict__ drug_emb,
                                               const float* __restrict__ prot_emb,
                                               const float* __restrict__ rowmax,
                                               const int* __restrict__ counts,
                                               const unsigned* __restrict__ colmax_enc,
                                               const unsigned* __restrict__ maskp,
                                               const float* __restrict__ W1,
                                               const float* __restrict__ b1,
                                               const float* __restrict__ W2,
                                               const float* __restrict__ b2,
                                               float* __restrict__ out) {
    int b = blockIdx.x;
    int t = threadIdx.x;
    int wid = t >> 6, lane = t & 63;

    __shared__ float att[LD];
    __shared__ int   sids[LD];
    __shared__ float redm[8], reds[8];
    __shared__ float part[8][HD];
    __shared__ float ew[PV];
    __shared__ float sInvP;
    __shared__ float comb[2 * HD];
    __shared__ float hpart[4][64];

    float r = -FLT_MAX;
    if (t < LD) {
        sids[t] = drug_ids[b * LD + t];
        r = rowmax[b * LD + t];
        float m = r;
        #pragma unroll
        for (int off = 32; off; off >>= 1) m = fmaxf(m, __shfl_xor(m, off, 64));
        if (lane == 0) redm[wid] = m;
    }
    __syncthreads();
    float gm = fmaxf(fmaxf(fmaxf(redm[0], redm[1]), fmaxf(redm[2], redm[3])),
                     fmaxf(fmaxf(redm[4], redm[5]), fmaxf(redm[6], redm[7])));
    if (t < LD) {
        float e = expf(r - gm);
        att[t] = e;
        float ssum = e;
        #pragma unroll
        for (int off = 32; off; off >>= 1) ssum += __shfl_xor(ssum, off, 64);
        if (lane == 0) reds[wid] = ssum;
    }
    __syncthreads();
    float invD = 1.f / (reds[0] + reds[1] + reds[2] + reds[3] +
                        reds[4] + reds[5] + reds[6] + reds[7]);

    // d_vec: 8 groups of 64 rows; (g,h) sums att[l]*drug_emb[ids[l]][h]
    {
        int h = t & 127, g = t >> 7;
        float acc = 0.f;
        #pragma unroll 4
        for (int i = 0; i < 64; ++i) {
            int l = g * 64 + i;
            acc = fmaf(att[l], drug_emb[(size_t)sids[l] * HD + h], acc);
        }
        part[g][h] = acc;
    }

    // protein softmax weights (wave 0, lanes 0..31)
    unsigned msk = maskp[b];
    if (t < 32) {
        bool pres = (t < PV) && ((msk >> t) & 1);
        float cm = pres ? dec_f32(colmax_enc[b * PV + t]) : -FLT_MAX;
        float M = cm;
        #pragma unroll
        for (int off = 16; off; off >>= 1) M = fmaxf(M, __shfl_xor(M, off, 64));
        int c = (t < PV) ? counts[b * PV + t] : 0;
        float w = (c > 0) ? (float)c * expf(cm - M) : 0.f;
        float S = w;
        #pragma unroll
        for (int off = 16; off; off >>= 1) S += __shfl_xor(S, off, 64);
        if (t < PV) ew[t] = w;
        if (t == 0) sInvP = 1.f / S;
    }
    __syncthreads();

    // combined = [d_vec | p_vec]
    if (t < HD) {
        float d = part[0][t] + part[1][t] + part[2][t] + part[3][t] +
                  part[4][t] + part[5][t] + part[6][t] + part[7][t];
        comb[t] = d * invD;
    } else if (t < 2 * HD) {
        int h = t - HD;
        float acc = 0.f;
        #pragma unroll
        for (int v = 0; v < PV; ++v)
            acc = fmaf(ew[v], prot_emb[v * HD + h], acc);
        comb[HD + h] = acc * sInvP;
    }
    __syncthreads();

    // MLP layer 1: 4-way K split over 256 inputs
    if (t < 256) {
        int j = t & 63, seg = t >> 6;
        float acc = 0.f;
        #pragma unroll
        for (int k = 0; k < 64; ++k) {
            int kk = seg * 64 + k;
            acc = fmaf(comb[kk], W1[kk * 64 + j], acc);
        }
        hpart[seg][j] = acc;
    }
    __syncthreads();
    if (t < 64) {
        float hj = b1[t] + hpart[0][t] + hpart[1][t] + hpart[2][t] + hpart[3][t];
        hj = fmaxf(hj, 0.f);
        float o = hj * W2[t];
        #pragma unroll
        for (int off = 32; off; off >>= 1) o += __shfl_xor(o, off, 64);
        if (t == 0) out[b] = o + b2[0];
    }
}

extern "C" void kernel_launch(void* const* d_in, const int* in_sizes, int n_in,
                              void* d_out, int out_size, void* d_ws, size_t ws_size,
                              hipStream_t stream) {
    const int*   drug_ids = (const int*)d_in[0];
    const int*   prot_ids = (const int*)d_in[1];
    const float* drug_emb = (const float*)d_in[2];
    const float* prot_emb = (const float*)d_in[3];
    const float* W1 = (const float*)d_in[4];
    const float* b1 = (const float*)d_in[5];
    const float* W2 = (const float*)d_in[6];
    const float* b2 = (const float*)d_in[7];
    float* out = (float*)d_out;

    char* ws = (char*)d_ws;
    int*      counts     = (int*)(ws + 0);
    unsigned* colmax_enc = (unsigned*)(ws + 3328);
    float*    rowmax     = (float*)(ws + 6656);
    unsigned* maskp      = (unsigned*)(ws + 72192);

    k_hist<<<NB, 256, 0, stream>>>(prot_ids, counts, colmax_enc, maskp);
    k_scores<<<NB * 8, 256, 0, stream>>>(drug_ids, drug_emb, prot_emb, maskp,
                                         rowmax, colmax_enc);
    k_tail<<<NB, 1024, 0, stream>>>(drug_ids, drug_emb, prot_emb, rowmax,
                                    counts, colmax_enc, maskp,
                                    W1, b1, W2, b2, out);
}